// Round 3
// baseline (395.171 us; speedup 1.0000x reference)
//
#include <hip/hip_runtime.h>

// CostVolume: out[b,c,h,x,d] = (x>=d) ? left[b,c,h,x] - right[b,c,h,x-d] : 0
// B=4, C=32, H=128, W=240, D=24 (fp32 in/out). Write-bound: 377.5 MB out,
// 31.5 MB in -> ~65 us floor at 6.3 TB/s achievable.
//
// R4 = R3 with compile fix: __builtin_nontemporal_store requires a native
// clang ext_vector type, not HIP's struct float4. Same single lever:
// non-temporal stores to kill the suspected fetch-on-write (RFO) that
// doubles HBM traffic. Evidence: harness poison fill writes 1.5 GB with
// FETCH_SIZE=14.5 KB at 6.25 TB/s; our kernel ran at ~2.9 TB/s effective.

typedef float floatx4 __attribute__((ext_vector_type(4)));

constexpr int W_IMG     = 240;
constexpr int D_LEV     = 24;
constexpr int ROWS_PB   = 8;                               // rows per block
constexpr int FLOATS_PB = ROWS_PB * W_IMG;                 // 1920 floats/image
constexpr int F4_STAGE  = FLOATS_PB / 4;                   // 480 float4 stages
constexpr int Q_PER_BLK = ROWS_PB * W_IMG * D_LEV / 4;     // 11520 float4 out
constexpr int ITERS     = Q_PER_BLK / 256;                 // 45, exact

__global__ __launch_bounds__(256) void cost_volume_kernel(
    const floatx4* __restrict__ left4,
    const floatx4* __restrict__ right4,
    floatx4* __restrict__ out4)
{
    __shared__ float lrow[FLOATS_PB];
    __shared__ float rrow[FLOATS_PB];

    const int t = threadIdx.x;
    const long long blk = blockIdx.x;
    const int sbase = (int)blk * F4_STAGE;     // <= 2047*480, fits int

    // Stage 8 left rows + 8 right rows: contiguous 7.68 KB each, coalesced.
    for (int s = t; s < F4_STAGE; s += 256)
        ((floatx4*)lrow)[s] = left4[sbase + s];
    for (int s = t; s < F4_STAGE; s += 256)
        ((floatx4*)rrow)[s] = right4[sbase + s];
    __syncthreads();

    floatx4* __restrict__ out_blk = out4 + blk * Q_PER_BLK;

    #pragma unroll 5
    for (int it = 0; it < ITERS; ++it) {
        const int q   = t + it * 256;      // 0 .. 11519, no tail
        const int pg  = q / 6;             // flat pixel index 0 .. 1919 (magic-mul)
        const int j   = q - pg * 6;        // float4 group within pixel: d = 4j+k
        const int pix = pg % 240;          // column within row (magic-mul)
        const int d0  = 4 * j;

        const float lv = lrow[pg];
        const int f = pg - d0;             // flat right index for k=0
        const int c = pix - d0;            // validity: need c >= k

        floatx4 o;
        { int fi = f;     float r = rrow[fi > 0 ? fi : 0]; o.x = (c >= 0) ? lv - r : 0.0f; }
        { int fi = f - 1; float r = rrow[fi > 0 ? fi : 0]; o.y = (c >= 1) ? lv - r : 0.0f; }
        { int fi = f - 2; float r = rrow[fi > 0 ? fi : 0]; o.z = (c >= 2) ? lv - r : 0.0f; }
        { int fi = f - 3; float r = rrow[fi > 0 ? fi : 0]; o.w = (c >= 3) ? lv - r : 0.0f; }

        // Non-temporal: bypass L2 allocation (no fetch-on-write).
        __builtin_nontemporal_store(o, &out_blk[q]);
    }
}

extern "C" void kernel_launch(void* const* d_in, const int* in_sizes, int n_in,
                              void* d_out, int out_size, void* d_ws, size_t ws_size,
                              hipStream_t stream) {
    const float* left  = (const float*)d_in[0];
    const float* right = (const float*)d_in[1];
    float*       out   = (float*)d_out;

    const int n_pix  = in_sizes[0];            // B*C*H*W
    const int rows   = n_pix / W_IMG;          // 16384
    const int blocks = rows / ROWS_PB;         // 2048

    cost_volume_kernel<<<blocks, 256, 0, stream>>>(
        (const floatx4*)left, (const floatx4*)right, (floatx4*)out);
}